// Round 8
// baseline (134.781 us; speedup 1.0000x reference)
//
#include <hip/hip_runtime.h>

typedef __attribute__((ext_vector_type(8))) short short8;
typedef __attribute__((ext_vector_type(4))) float f32x4;
typedef unsigned short u16;
typedef unsigned int u32;
typedef __attribute__((address_space(1))) const u32 gu32;
typedef __attribute__((address_space(3))) u32 lu32;

// ---------- bf16 helpers ----------
__device__ __forceinline__ u16 f2bf(float f){
  unsigned u = __float_as_uint(f);
  u += 0x7FFF + ((u >> 16) & 1);          // round-to-nearest-even
  return (u16)(u >> 16);
}
__device__ __forceinline__ float bf2f(u16 h){ return __uint_as_float(((unsigned)h) << 16); }

// ---------- problem constants ----------
#define BB   16
#define NN   1024
#define DML  512
#define DL   256
#define DM   128
#define NC   10
#define SK   140
#define KTOT (NN*DM)          // 131072

// ---------- K_prep: pack weights bf16-transposed | transpose W_final -> bf16 ----------
__global__ void k_prep(const float* __restrict__ Wlin, const float* __restrict__ Wq,
                       const float* __restrict__ Wk, const float* __restrict__ Wv,
                       const float* __restrict__ Wadd,
                       u16* __restrict__ wlinT, u16* __restrict__ w4T,
                       const float* __restrict__ Wf, u16* __restrict__ wfT){
  int blk = blockIdx.x, t = threadIdx.x;
  if (blk < 512){
    int id = blk*256 + t;              // 131072
    {
      int j = id >> 9;        // 0..255  (DL)
      int k = id & 511;       // 0..511  (DML)
      wlinT[id] = f2bf(Wlin[k*DL + j]);   // wlinT[j][k] = Wlin[k][j]
    }
    {
      int j = id >> 8;        // 0..511  (4*DM)
      int k = id & 255;       // 0..255  (DL)
      const float* src = (j < 128) ? Wq : (j < 256) ? Wk : (j < 384) ? Wv : Wadd;
      int jj = j & 127;
      w4T[id] = f2bf(src[k*DM + jj]);     // w4T[n][j] = W4[j][n]
    }
  } else {
    __shared__ float sT[2560];
    int b2 = blk - 512;                // 0..511
    long base = (long)b2 * 2560;
    for (int i = t; i < 2560; i += 256) sT[i] = Wf[base + i];
    __syncthreads();
    int k0 = b2 * 256;
    for (int j = t; j < 2560; j += 256){
      int c = j >> 8, kk = j & 255;
      wfT[(long)c*KTOT + k0 + kk] = f2bf(sT[kk*NC + c]);
    }
  }
}

// ---------- K_wcomb: Wc[n][k] = sum_j Wlin[k][j]*W4[j][n]  (bf16), bc[n] = b_lin@W4 (+b_add) ----------
// grid 64 blocks x 512 threads; block handles 8 n-columns, thread handles k = t.
__global__ __launch_bounds__(512) void k_wcomb(const u16* __restrict__ wlinT, const u16* __restrict__ w4T,
                                               const float* __restrict__ blin, const float* __restrict__ badd,
                                               u16* __restrict__ wcT, float* __restrict__ bc){
  __shared__ float s4[8][256];
  __shared__ float rs[4][8];
  int n0 = blockIdx.x*8, t = threadIdx.x;
  for (int i = t; i < 2048; i += 512){
    int c = i >> 8, j = i & 255;
    s4[c][j] = bf2f(w4T[(n0+c)*256 + j]);
  }
  __syncthreads();
  float acc[8] = {0,0,0,0,0,0,0,0};
  for (int j = 0; j < 256; ++j){
    float wl = bf2f(wlinT[j*512 + t]);
    #pragma unroll
    for (int c = 0; c < 8; ++c) acc[c] += wl * s4[c][j];
  }
  #pragma unroll
  for (int c = 0; c < 8; ++c) wcT[(long)(n0+c)*512 + t] = f2bf(acc[c]);
  // bias
  if (t < 256){
    float bl = blin[t];
    float pb[8];
    #pragma unroll
    for (int c = 0; c < 8; ++c) pb[c] = bl * s4[c][t];
    #pragma unroll
    for (int o = 32; o; o >>= 1)
      #pragma unroll
      for (int c = 0; c < 8; ++c) pb[c] += __shfl_xor(pb[c], o);
    if ((t & 63) == 0){
      #pragma unroll
      for (int c = 0; c < 8; ++c) rs[t>>6][c] = pb[c];
    }
  }
  __syncthreads();
  if (t < 8){
    float s = rs[0][t] + rs[1][t] + rs[2][t] + rs[3][t];
    int n = n0 + t;
    if (n >= 384) s += badd[n - 384];
    bc[n] = s;
  }
}

// ---------- K_qkva: [Q|K|V|A] = emb(f32) @ Wc + bc -> bf16 ; BM=64 x BN=512, emb read ONCE ----------
__global__ __launch_bounds__(512) void k_qkva(const float* __restrict__ A, const u16* __restrict__ Bw,
                                              const float* __restrict__ bc,
                                              u16* __restrict__ oq, u16* __restrict__ ok,
                                              u16* __restrict__ ov, u16* __restrict__ oa){
  __shared__ u16 sA[64*64];     // 8KB
  __shared__ u16 sB[512*64];    // 64KB
  const int tid  = threadIdx.x;
  const int lane = tid & 63;
  const int wave = tid >> 6;    // 0..7, wave owns cols [wave*64, wave*64+64)
  int m0 = blockIdx.x*64;
  f32x4 acc[4][4];
  f32x4 z = {0.f,0.f,0.f,0.f};
  #pragma unroll
  for (int m_=0;m_<4;++m_) for (int n_=0;n_<4;++n_) acc[m_][n_] = z;

  const int arow = tid >> 3, aq = tid & 7;   // A: 64 rows x 8 chunks(8 f32)
  f32x4 ra[2];
  short8 rb[8];

  // prologue: load tile 0 to regs
  {
    const float* src = A + (long)(m0+arow)*DML + aq*8;
    ra[0] = ((const f32x4*)src)[0]; ra[1] = ((const f32x4*)src)[1];
    #pragma unroll
    for (int i=0;i<8;++i){
      int ci = i*512 + tid, row = ci>>3, kc = ci&7;
      rb[i] = *(const short8*)(Bw + (long)row*512 + kc*8);
    }
  }
  // store tile 0
  {
    short8 o;
    #pragma unroll
    for (int j=0;j<4;++j){ o[j]=(short)f2bf(ra[0][j]); o[4+j]=(short)f2bf(ra[1][j]); }
    *(short8*)&sA[arow*64 + ((aq ^ (arow&7))<<3)] = o;
    #pragma unroll
    for (int i=0;i<8;++i){
      int ci = i*512 + tid, row = ci>>3, kc = ci&7;
      *(short8*)&sB[row*64 + ((kc ^ (row&7))<<3)] = rb[i];
    }
  }
  __syncthreads();

  for (int tt = 0; tt < 8; ++tt){
    if (tt < 7){
      int kb = (tt+1)*64;
      const float* src = A + (long)(m0+arow)*DML + kb + aq*8;
      ra[0] = ((const f32x4*)src)[0]; ra[1] = ((const f32x4*)src)[1];
      #pragma unroll
      for (int i=0;i<8;++i){
        int ci = i*512 + tid, row = ci>>3, kc = ci&7;
        rb[i] = *(const short8*)(Bw + (long)row*512 + kb + kc*8);
      }
    }
    #pragma unroll
    for (int kk = 0; kk < 2; ++kk){
      short8 af[4], bfr[4];
      int cb = kk*4 + (lane >> 4);
      #pragma unroll
      for (int m_=0; m_<4; ++m_){
        int row = m_*16 + (lane & 15);
        af[m_] = *(const short8*)&sA[row*64 + ((cb ^ (row & 7)) << 3)];
      }
      #pragma unroll
      for (int n_=0; n_<4; ++n_){
        int row = wave*64 + n_*16 + (lane & 15);
        bfr[n_] = *(const short8*)&sB[row*64 + ((cb ^ (row & 7)) << 3)];
      }
      #pragma unroll
      for (int m_=0; m_<4; ++m_)
        #pragma unroll
        for (int n_=0; n_<4; ++n_)
          acc[m_][n_] = __builtin_amdgcn_mfma_f32_16x16x32_bf16(af[m_], bfr[n_], acc[m_][n_], 0, 0, 0);
    }
    __syncthreads();
    if (tt < 7){
      short8 o;
      #pragma unroll
      for (int j=0;j<4;++j){ o[j]=(short)f2bf(ra[0][j]); o[4+j]=(short)f2bf(ra[1][j]); }
      *(short8*)&sA[arow*64 + ((aq ^ (arow&7))<<3)] = o;
      #pragma unroll
      for (int i=0;i<8;++i){
        int ci = i*512 + tid, row = ci>>3, kc = ci&7;
        *(short8*)&sB[row*64 + ((kc ^ (row&7))<<3)] = rb[i];
      }
      __syncthreads();
    }
  }

  int mat = wave >> 1;   // 0=Q 1=K 2=V 3=A
  u16* dst = (mat==0) ? oq : (mat==1) ? ok : (mat==2) ? ov : oa;
  #pragma unroll
  for (int m_=0;m_<4;++m_)
    #pragma unroll
    for (int n_=0;n_<4;++n_)
      #pragma unroll
      for (int rr=0;rr<4;++rr){
        int gn  = wave*64 + n_*16 + (lane & 15);
        int row = m0 + m_*16 + (lane>>4)*4 + rr;
        int cl  = gn & 127;
        dst[(long)row*DM + cl] = f2bf(acc[m_][n_][rr] + bc[gn]);
      }
}

// ---------- GEMM staging helpers (128-row tiles, BK=64) ----------
__device__ __forceinline__ void stage2(const u16* __restrict__ A, const u16* __restrict__ B,
                                       int K, int m0, int n0, int kb,
                                       u16* sA, u16* sB, int tid, int wave){
  #pragma unroll
  for (int i = 0; i < 4; ++i){
    int ci  = i*256 + tid;
    int row = ci >> 3;
    int kc  = (ci & 7) ^ (row & 7);
    __builtin_amdgcn_global_load_lds((gu32*)(A + (long)(m0+row)*K + kb + kc*8),
                                     (lu32*)(sA + (i*256 + wave*64)*8), 16, 0, 0);
    __builtin_amdgcn_global_load_lds((gu32*)(B + (long)(n0+row)*K + kb + kc*8),
                                     (lu32*)(sB + (i*256 + wave*64)*8), 16, 0, 0);
  }
}
__device__ __forceinline__ void compute64(const u16* sA, const u16* sB,
                                          int lane, int wrow, int wcol, f32x4 acc[4][4]){
  #pragma unroll
  for (int kk = 0; kk < 2; ++kk){
    short8 af[4], bfr[4];
    int cb = kk*4 + (lane >> 4);
    #pragma unroll
    for (int m_=0; m_<4; ++m_){
      int row = wrow + m_*16 + (lane & 15);
      af[m_] = *(const short8*)&sA[row*64 + ((cb ^ (row & 7)) << 3)];
    }
    #pragma unroll
    for (int n_=0; n_<4; ++n_){
      int row = wcol + n_*16 + (lane & 15);
      bfr[n_] = *(const short8*)&sB[row*64 + ((cb ^ (row & 7)) << 3)];
    }
    #pragma unroll
    for (int m_=0; m_<4; ++m_)
      #pragma unroll
      for (int n_=0; n_<4; ++n_)
        acc[m_][n_] = __builtin_amdgcn_mfma_f32_16x16x32_bf16(af[m_], bfr[n_], acc[m_][n_], 0, 0, 0);
  }
}
__device__ __forceinline__ void gemm_core_db(const u16* __restrict__ A, const u16* __restrict__ B,
                                             int K, int m0, int n0,
                                             u16* sA0, u16* sB0, u16* sA1, u16* sB1,
                                             f32x4 acc[4][4]){
  const int tid  = threadIdx.x;
  const int lane = tid & 63;
  const int wave = tid >> 6;
  const int wrow = (wave >> 1) * 64;
  const int wcol = (wave & 1) * 64;
  u16 *cA = sA0, *cB = sB0, *nA = sA1, *nB = sB1;
  stage2(A, B, K, m0, n0, 0, cA, cB, tid, wave);
  __syncthreads();
  int nt = K >> 6;
  for (int t = 0; t < nt-1; ++t){
    stage2(A, B, K, m0, n0, (t+1)*64, nA, nB, tid, wave);
    compute64(cA, cB, lane, wrow, wcol, acc);
    __syncthreads();
    u16* x;
    x = cA; cA = nA; nA = x;
    x = cB; cB = nB; nB = x;
  }
  compute64(cA, cB, lane, wrow, wcol, acc);
}

// ---------- K4: S[b] = Q[b] @ K[b]^T -> bf16 ----------
__global__ __launch_bounds__(256) void k_gemm_s(const u16* __restrict__ Q, const u16* __restrict__ Km,
                                                u16* __restrict__ S){
  __shared__ u16 sA0[128*64], sB0[128*64], sA1[128*64], sB1[128*64];
  f32x4 acc[4][4];
  f32x4 z = {0.f,0.f,0.f,0.f};
  #pragma unroll
  for (int m_=0;m_<4;++m_) for (int n_=0;n_<4;++n_) acc[m_][n_] = z;
  int b  = blockIdx.z;
  int m0 = blockIdx.x*128, n0 = blockIdx.y*128;
  const u16* A = Q  + (long)b*NN*DM;
  const u16* B = Km + (long)b*NN*DM;
  gemm_core_db(A, B, DM, m0, n0, sA0, sB0, sA1, sB1, acc);
  int lane = threadIdx.x & 63, wave = threadIdx.x >> 6;
  int wrow = (wave>>1)*64, wcol = (wave&1)*64;
  u16* Sb = S + (long)b*NN*NN;
  #pragma unroll
  for (int m_=0;m_<4;++m_)
    #pragma unroll
    for (int n_=0;n_<4;++n_)
      #pragma unroll
      for (int r=0;r<4;++r){
        int row = m0 + wrow + m_*16 + (lane>>4)*4 + r;
        int col = n0 + wcol + n_*16 + (lane & 15);
        Sb[(long)row*NN + col] = f2bf(acc[m_][n_][r]);
      }
}

// ---------- K5: M via LDS-staged coalesced S rows + LDS gather ----------
// grid (NN/8, BB), 256 threads; block loads 8 S rows (16KB) + 1120 idx ints, gathers from LDS.
__global__ __launch_bounds__(256) void k_mscore(const u16* __restrict__ S, const int* __restrict__ idx,
                                                float* __restrict__ M){
  __shared__ u16 sS[8*1024];     // 16KB
  __shared__ int sI[8*SK];       // 4.5KB
  int b = blockIdx.y, l0 = blockIdx.x*8, t = threadIdx.x;
  const u16* Sb = S + (long)b*NN*NN + (long)l0*NN;
  #pragma unroll
  for (int i = 0; i < 4; ++i){
    int ci = i*256 + t;          // 1024 chunks of 16B
    *(short8*)&sS[ci*8] = *(const short8*)(Sb + ci*8);
  }
  for (int i = t; i < 8*SK; i += 256) sI[i] = idx[l0*SK + i];
  __syncthreads();
  int r = t >> 5, g = t & 31;    // 32 lanes per row
  const int* ir = sI + r*SK;
  const u16* sr = sS + r*1024;
  float mx = -1e30f, sm = 0.f;
  for (int s = g; s < SK; s += 32){
    float v = bf2f(sr[ir[s]]);
    mx = fmaxf(mx, v); sm += v;
  }
  #pragma unroll
  for (int o=16;o;o>>=1){ mx = fmaxf(mx, __shfl_xor(mx,o)); sm += __shfl_xor(sm,o); }
  if (g == 0) M[b*NN + l0 + r] = mx - sm * (1.0f/1024.0f);
}

// ---------- K6a: partial ranks (blocks 0..255) + V column-mean (blocks 256..271) ----------
__global__ __launch_bounds__(256) void k_rankvm(const float* __restrict__ M, int* __restrict__ partial,
                                                const u16* __restrict__ V, float* __restrict__ vmean){
  __shared__ float sC[64];
  __shared__ float red[16][128];
  int blk = blockIdx.x, t = threadIdx.x;
  if (blk < 256){
    int jc = blk & 15, b = blk >> 4;
    const float* Mb = M + b*NN;
    if (t < 64) sC[t] = Mb[jc*64 + t];
    __syncthreads();
    int j0 = jc*64;
    float mi[4];
    int cnt[4] = {0,0,0,0};
    #pragma unroll
    for (int r=0;r<4;++r) mi[r] = Mb[t + r*256];
    for (int j = 0; j < 64; ++j){
      float mj = sC[j];
      int jg = j0 + j;
      #pragma unroll
      for (int r=0;r<4;++r){
        int i = t + r*256;
        cnt[r] += (mj > mi[r]) || (mj == mi[r] && jg < i);
      }
    }
    int* pb = partial + (b*16 + jc)*NN;
    #pragma unroll
    for (int r=0;r<4;++r) pb[t + r*256] = cnt[r];
  } else {
    int b = blk - 256;
    int d8 = t & 15, seg = t >> 4;
    const u16* Vb = V + (long)b*KTOT + seg*64*DM + d8*8;
    float acc[8] = {0,0,0,0,0,0,0,0};
    for (int l = 0; l < 64; ++l){
      short8 v = *(const short8*)(Vb + l*DM);
      #pragma unroll
      for (int j=0;j<8;++j) acc[j] += bf2f((u16)v[j]);
    }
    #pragma unroll
    for (int j=0;j<8;++j) red[seg][d8*8+j] = acc[j];
    __syncthreads();
    if (t < 128){
      float s = 0.f;
      #pragma unroll
      for (int g=0;g<16;++g) s += red[g][t];
      vmean[b*DM + t] = s * (1.0f/1024.0f);
    }
  }
}

// ---------- K6b: sum partial ranks -> mtop + selmap ----------
__global__ __launch_bounds__(1024) void k_sel(const int* __restrict__ partial, int* __restrict__ mtop,
                                              int* __restrict__ selmap){
  int b = blockIdx.x, i = threadIdx.x;
  int cnt = 0;
  #pragma unroll
  for (int jc = 0; jc < 16; ++jc) cnt += partial[(b*16 + jc)*NN + i];
  selmap[b*NN + i] = (cnt < SK) ? cnt : -1;
  if (cnt < SK) mtop[b*SK + cnt] = i;
}

// ---------- K9: softmax(S_row/sqrt(d)) @ V for top-140 rows, 4 rows/block ----------
__global__ __launch_bounds__(256) void k_attn(const u16* __restrict__ S, const u16* __restrict__ V,
                                              const int* __restrict__ mtop, float* __restrict__ upd){
  __shared__ float sE[4][1024];
  __shared__ float redM[4][4];
  __shared__ float redS[4][4];
  int b = blockIdx.y, u0 = blockIdx.x*4, t = threadIdx.x;
  int lane = t & 63, wave = t >> 6;
  const float inv = 0.08838834764831845f;   // 1/sqrt(128)

  int rows[4];
  #pragma unroll
  for (int r=0;r<4;++r) rows[r] = mtop[b*SK + u0 + r];

  float sv[4][4];
  float pm[4];
  const u16* Sb = S + (long)b*NN*NN;
  #pragma unroll
  for (int r=0;r<4;++r){
    ushort4 raw = ((const ushort4*)(Sb + (long)rows[r]*NN))[t];
    sv[r][0] = bf2f(raw.x)*inv; sv[r][1] = bf2f(raw.y)*inv;
    sv[r][2] = bf2f(raw.z)*inv; sv[r][3] = bf2f(raw.w)*inv;
    pm[r] = fmaxf(fmaxf(sv[r][0],sv[r][1]), fmaxf(sv[r][2],sv[r][3]));
  }
  #pragma unroll
  for (int o=32;o;o>>=1)
    #pragma unroll
    for (int r=0;r<4;++r) pm[r] = fmaxf(pm[r], __shfl_xor(pm[r],o));
  if (lane == 0){
    #pragma unroll
    for (int r=0;r<4;++r) redM[wave][r] = pm[r];
  }
  __syncthreads();
  float mx[4], ps[4];
  #pragma unroll
  for (int r=0;r<4;++r)
    mx[r] = fmaxf(fmaxf(redM[0][r],redM[1][r]), fmaxf(redM[2][r],redM[3][r]));
  #pragma unroll
  for (int r=0;r<4;++r){
    float s = 0.f;
    #pragma unroll
    for (int j=0;j<4;++j){
      float e = __expf(sv[r][j] - mx[r]);
      sE[r][t*4+j] = e;
      s += e;
    }
    ps[r] = s;
  }
  #pragma unroll
  for (int o=32;o;o>>=1)
    #pragma unroll
    for (int r=0;r<4;++r) ps[r] += __shfl_xor(ps[r],o);
  if (lane == 0){
    #pragma unroll
    for (int r=0;r<4;++r) redS[wave][r] = ps[r];
  }
  __syncthreads();
  float rZ[4];
  #pragma unroll
  for (int r=0;r<4;++r)
    rZ[r] = 1.0f / (redS[0][r]+redS[1][r]+redS[2][r]+redS[3][r]);

  int kg = t & 15;
  int dg = t >> 4;
  const u16* Vb = V + (long)b*KTOT + dg*8;
  float acc[4][8];
  #pragma unroll
  for (int r=0;r<4;++r)
    #pragma unroll
    for (int j=0;j<8;++j) acc[r][j] = 0.f;

  for (int k = kg; k < NN; k += 16){
    short8 v = *(const short8*)(Vb + (long)k*DM);
    float vf[8];
    #pragma unroll
    for (int j=0;j<8;++j) vf[j] = bf2f((u16)v[j]);
    #pragma unroll
    for (int r=0;r<4;++r){
      float e = sE[r][k];
      #pragma unroll
      for (int j=0;j<8;++j) acc[r][j] += e * vf[j];
    }
  }

  #pragma unroll
  for (int o=1;o<16;o<<=1)
    #pragma unroll
    for (int r=0;r<4;++r)
      #pragma unroll
      for (int j=0;j<8;++j) acc[r][j] += __shfl_xor(acc[r][j], o);

  if (kg == 0){
    #pragma unroll
    for (int r=0;r<4;++r){
      float* dst = upd + ((long)b*SK + u0 + r)*DM + dg*8;
      float4 o1 = {acc[r][0]*rZ[r], acc[r][1]*rZ[r], acc[r][2]*rZ[r], acc[r][3]*rZ[r]};
      float4 o2 = {acc[r][4]*rZ[r], acc[r][5]*rZ[r], acc[r][6]*rZ[r], acc[r][7]*rZ[r]};
      ((float4*)dst)[0] = o1;
      ((float4*)dst)[1] = o2;
    }
  }
}

// ---------- K11: final GEMV partials: (ctx+A) @ W_final ----------
__global__ __launch_bounds__(256) void k_final(const float* __restrict__ upd, const float* __restrict__ vmean,
                                               const int* __restrict__ selmap,
                                               const u16* __restrict__ Aad,
                                               const u16* __restrict__ wfT, float* __restrict__ part){
  int b = blockIdx.x, ch = blockIdx.y, t = threadIdx.x;
  long base = (long)b * KTOT;
  int k0 = ch * 4096;
  float acc[NC] = {0.f};
  for (int k = k0 + t; k < k0 + 4096; k += 256){
    int l = k >> 7, d = k & 127;
    int sel = selmap[b*NN + l];
    float c = (sel >= 0) ? upd[((long)b*SK + sel)*DM + d] : vmean[b*DM + d];
    float v = c + bf2f(Aad[base + k]);
    #pragma unroll
    for (int cc = 0; cc < NC; ++cc) acc[cc] += v * bf2f(wfT[cc*KTOT + k]);
  }
  __shared__ float lred[40];
  int lane = t & 63, wave = t >> 6;
  #pragma unroll
  for (int c = 0; c < NC; ++c){
    float v = acc[c];
    #pragma unroll
    for (int o=32;o;o>>=1) v += __shfl_xor(v,o);
    if (lane == 0) lred[wave*NC + c] = v;
  }
  __syncthreads();
  if (t < NC) part[(b*32 + ch)*NC + t] = lred[t] + lred[NC+t] + lred[2*NC+t] + lred[3*NC+t];
}

// ---------- K12: reduce partials + bias -> out ----------
__global__ void k_out(const float* __restrict__ part, const float* __restrict__ bfin, float* __restrict__ out){
  int t = threadIdx.x;
  if (t < BB*NC){
    int b = t / NC, c = t % NC;
    float s = bfin[c];
    #pragma unroll
    for (int ch = 0; ch < 32; ++ch) s += part[(b*32 + ch)*NC + c];
    out[t] = s;
  }
}

// ---------- launch ----------
extern "C" void kernel_launch(void* const* d_in, const int* in_sizes, int n_in,
                              void* d_out, int out_size, void* d_ws, size_t ws_size,
                              hipStream_t stream){
  const float* emb  = (const float*)d_in[0];
  const int*   idxs = (const int*)  d_in[1];
  const float* Wlin = (const float*)d_in[2];
  const float* blin = (const float*)d_in[3];
  const float* Wq   = (const float*)d_in[4];
  const float* Wk   = (const float*)d_in[5];
  const float* Wv   = (const float*)d_in[6];
  const float* Wadd = (const float*)d_in[7];
  const float* badd = (const float*)d_in[8];
  const float* Wfin = (const float*)d_in[9];
  const float* bfin = (const float*)d_in[10];
  float* out = (float*)d_out;

  char* p = (char*)d_ws;
  auto alloc = [&](size_t bytes)->char*{ char* r = p; p += (bytes + 255) & ~(size_t)255; return r; };
  u16*   wlinT  = (u16*)  alloc((size_t)DL*DML*2);
  u16*   w4T    = (u16*)  alloc((size_t)4*DM*DL*2);
  u16*   wcT    = (u16*)  alloc((size_t)512*512*2);
  float* bc     = (float*)alloc((size_t)512*4);
  u16*   q_bf   = (u16*)  alloc((size_t)BB*NN*DM*2);
  u16*   k_bf   = (u16*)  alloc((size_t)BB*NN*DM*2);
  u16*   v_bf   = (u16*)  alloc((size_t)BB*NN*DM*2);
  u16*   a_bf   = (u16*)  alloc((size_t)BB*NN*DM*2);
  u16*   s_bf   = (u16*)  alloc((size_t)BB*NN*NN*2);
  float* m_f    = (float*)alloc((size_t)BB*NN*4);
  int*   rankp  = (int*)  alloc((size_t)BB*16*NN*4);
  int*   mtop   = (int*)  alloc((size_t)BB*SK*4);
  int*   selmap = (int*)  alloc((size_t)BB*NN*4);
  float* vmean  = (float*)alloc((size_t)BB*DM*4);
  float* upd    = (float*)alloc((size_t)BB*SK*DM*4);
  u16*   wfT    = (u16*)  alloc((size_t)NC*KTOT*2);
  float* part   = (float*)alloc((size_t)BB*32*NC*4);

  // 1: pack weights + wfT
  k_prep<<<dim3(1024), dim3(256), 0, stream>>>(Wlin, Wq, Wk, Wv, Wadd, wlinT, w4T, Wfin, wfT);
  // 2: combined weight Wc = Wlin @ [Wq|Wk|Wv|Wadd], bias bc
  k_wcomb<<<dim3(64), dim3(512), 0, stream>>>(wlinT, w4T, blin, badd, wcT, bc);
  // 3: Q,K,V,A directly from emb (x eliminated)
  k_qkva<<<dim3(256), dim3(512), 0, stream>>>(emb, wcT, bc, q_bf, k_bf, v_bf, a_bf);
  // 4: S = Q K^T per batch
  k_gemm_s<<<dim3(8, 8, 16), dim3(256), 0, stream>>>(q_bf, k_bf, s_bf);
  // 5: M scores (LDS-staged coalesced)
  k_mscore<<<dim3(NN/8, BB), dim3(256), 0, stream>>>(s_bf, idxs, m_f);
  // 6: partial ranks + vmean
  k_rankvm<<<dim3(272), dim3(256), 0, stream>>>(m_f, rankp, v_bf, vmean);
  // 7: select top-140
  k_sel<<<dim3(BB), dim3(1024), 0, stream>>>(rankp, mtop, selmap);
  // 8: attention rows -> compact upd
  k_attn<<<dim3(SK/4, BB), dim3(256), 0, stream>>>(s_bf, v_bf, mtop, upd);
  // 9/10: final projection
  k_final<<<dim3(BB, 32), dim3(256), 0, stream>>>(upd, vmean, selmap, a_bf, wfT, part);
  k_out<<<dim3(1), dim3(256), 0, stream>>>(part, bfin, out);
}

// Round 9
// 121.270 us; speedup vs baseline: 1.1114x; 1.1114x over previous
//
#include <hip/hip_runtime.h>

typedef __attribute__((ext_vector_type(8))) short short8;
typedef __attribute__((ext_vector_type(4))) float f32x4;
typedef unsigned short u16;
typedef unsigned int u32;
typedef __attribute__((address_space(1))) const u32 gu32;
typedef __attribute__((address_space(3))) u32 lu32;

// ---------- bf16 helpers ----------
__device__ __forceinline__ u16 f2bf(float f){
  unsigned u = __float_as_uint(f);
  u += 0x7FFF + ((u >> 16) & 1);          // round-to-nearest-even
  return (u16)(u >> 16);
}
__device__ __forceinline__ float bf2f(u16 h){ return __uint_as_float(((unsigned)h) << 16); }

// ---------- problem constants ----------
#define BB   16
#define NN   1024
#define DML  512
#define DL   256
#define DM   128
#define NC   10
#define SK   140
#define KTOT (NN*DM)          // 131072

// ---------- K_prep: pack weights bf16-transposed | transpose W_final -> bf16 ----------
__global__ void k_prep(const float* __restrict__ Wlin, const float* __restrict__ Wq,
                       const float* __restrict__ Wk, const float* __restrict__ Wv,
                       const float* __restrict__ Wadd,
                       u16* __restrict__ wlinT, u16* __restrict__ w4T,
                       const float* __restrict__ Wf, u16* __restrict__ wfT){
  int blk = blockIdx.x, t = threadIdx.x;
  if (blk < 512){
    int id = blk*256 + t;              // 131072
    {
      int j = id >> 9;        // 0..255  (DL)
      int k = id & 511;       // 0..511  (DML)
      wlinT[id] = f2bf(Wlin[k*DL + j]);
    }
    {
      int j = id >> 8;        // 0..511  (4*DM)
      int k = id & 255;       // 0..255  (DL)
      const float* src = (j < 128) ? Wq : (j < 256) ? Wk : (j < 384) ? Wv : Wadd;
      int jj = j & 127;
      w4T[id] = f2bf(src[k*DM + jj]);
    }
  } else {
    __shared__ float sT[2560];
    int b2 = blk - 512;                // 0..511
    long base = (long)b2 * 2560;
    for (int i = t; i < 2560; i += 256) sT[i] = Wf[base + i];
    __syncthreads();
    int k0 = b2 * 256;
    for (int j = t; j < 2560; j += 256){
      int c = j >> 8, kk = j & 255;
      wfT[(long)c*KTOT + k0 + kk] = f2bf(sT[kk*NC + c]);
    }
  }
}

// ---------- GEMM staging helpers (128-row tiles, BK=64) ----------
__device__ __forceinline__ void stage2(const u16* __restrict__ A, const u16* __restrict__ B,
                                       int K, int m0, int n0, int kb,
                                       u16* sA, u16* sB, int tid, int wave){
  #pragma unroll
  for (int i = 0; i < 4; ++i){
    int ci  = i*256 + tid;
    int row = ci >> 3;
    int kc  = (ci & 7) ^ (row & 7);
    __builtin_amdgcn_global_load_lds((gu32*)(A + (long)(m0+row)*K + kb + kc*8),
                                     (lu32*)(sA + (i*256 + wave*64)*8), 16, 0, 0);
    __builtin_amdgcn_global_load_lds((gu32*)(B + (long)(n0+row)*K + kb + kc*8),
                                     (lu32*)(sB + (i*256 + wave*64)*8), 16, 0, 0);
  }
}
// MFMA over one 64-wide K tile (128x128 tile, 4 waves of 64x64)
__device__ __forceinline__ void compute64(const u16* sA, const u16* sB,
                                          int lane, int wrow, int wcol, f32x4 acc[4][4]){
  #pragma unroll
  for (int kk = 0; kk < 2; ++kk){
    short8 af[4], bfr[4];
    int cb = kk*4 + (lane >> 4);
    #pragma unroll
    for (int m_=0; m_<4; ++m_){
      int row = wrow + m_*16 + (lane & 15);
      af[m_] = *(const short8*)&sA[row*64 + ((cb ^ (row & 7)) << 3)];
    }
    #pragma unroll
    for (int n_=0; n_<4; ++n_){
      int row = wcol + n_*16 + (lane & 15);
      bfr[n_] = *(const short8*)&sB[row*64 + ((cb ^ (row & 7)) << 3)];
    }
    #pragma unroll
    for (int m_=0; m_<4; ++m_)
      #pragma unroll
      for (int n_=0; n_<4; ++n_)
        acc[m_][n_] = __builtin_amdgcn_mfma_f32_16x16x32_bf16(af[m_], bfr[n_], acc[m_][n_], 0, 0, 0);
  }
}
// double-buffered core: 1 barrier per K-step, stage(next) overlaps compute(cur)
__device__ __forceinline__ void gemm_core_db(const u16* __restrict__ A, const u16* __restrict__ B,
                                             int K, int m0, int n0,
                                             u16* sA0, u16* sB0, u16* sA1, u16* sB1,
                                             f32x4 acc[4][4]){
  const int tid  = threadIdx.x;
  const int lane = tid & 63;
  const int wave = tid >> 6;
  const int wrow = (wave >> 1) * 64;
  const int wcol = (wave & 1) * 64;
  u16 *cA = sA0, *cB = sB0, *nA = sA1, *nB = sB1;
  stage2(A, B, K, m0, n0, 0, cA, cB, tid, wave);
  __syncthreads();
  int nt = K >> 6;
  for (int t = 0; t < nt-1; ++t){
    stage2(A, B, K, m0, n0, (t+1)*64, nA, nB, tid, wave);
    compute64(cA, cB, lane, wrow, wcol, acc);
    __syncthreads();
    u16* x;
    x = cA; cA = nA; nA = x;
    x = cB; cB = nB; nB = x;
  }
  compute64(cA, cB, lane, wrow, wcol, acc);
}

// ---------- K2: x = emb(f32) @ W_lin + b_lin -> bf16 ; BM=64 x BN=128, 2 blocks-deep N-split ----------
__global__ __launch_bounds__(256) void k_gemm_x(const float* __restrict__ A, const u16* __restrict__ B,
                                                const float* __restrict__ bias, u16* __restrict__ out){
  __shared__ u16 sA[64*64];     // 8KB
  __shared__ u16 sB[128*64];    // 16KB
  const int tid  = threadIdx.x;
  const int lane = tid & 63;
  const int wave = tid >> 6;
  const int wrow = (wave >> 1) * 32;
  const int wcol = (wave & 1) * 64;
  int m0 = blockIdx.x*64, n0 = blockIdx.y*128;
  f32x4 acc[2][4];
  f32x4 z = {0.f,0.f,0.f,0.f};
  #pragma unroll
  for (int m_=0;m_<2;++m_) for (int n_=0;n_<4;++n_) acc[m_][n_] = z;

  f32x4 ra[4];      // A: 16 f32 per thread (row = tid>>2, two chunks kc=aq*2, aq*2+1)
  short8 rb[4];     // B: 4 chunks per thread
  const int arow = tid >> 2, aq = tid & 3;

  // prologue: tile 0
  {
    const float* src = A + (long)(m0+arow)*DML + aq*16;
    ra[0] = ((const f32x4*)src)[0]; ra[1] = ((const f32x4*)src)[1];
    ra[2] = ((const f32x4*)src)[2]; ra[3] = ((const f32x4*)src)[3];
    #pragma unroll
    for (int i=0;i<4;++i){
      int ci = i*256 + tid, row = ci>>3, kc = ci&7;
      rb[i] = *(const short8*)(B + (long)(n0+row)*DML + kc*8);
    }
  }
  {
    short8 o0, o1;
    #pragma unroll
    for (int j=0;j<4;++j){ o0[j]=(short)f2bf(ra[0][j]); o0[4+j]=(short)f2bf(ra[1][j]);
                           o1[j]=(short)f2bf(ra[2][j]); o1[4+j]=(short)f2bf(ra[3][j]); }
    int kc0 = aq*2, kc1 = aq*2+1;
    *(short8*)&sA[arow*64 + ((kc0 ^ (arow&7))<<3)] = o0;
    *(short8*)&sA[arow*64 + ((kc1 ^ (arow&7))<<3)] = o1;
    #pragma unroll
    for (int i=0;i<4;++i){
      int ci = i*256 + tid, row = ci>>3, kc = ci&7;
      *(short8*)&sB[row*64 + ((kc ^ (row&7))<<3)] = rb[i];
    }
  }
  __syncthreads();

  for (int tt = 0; tt < 8; ++tt){
    if (tt < 7){
      int kb = (tt+1)*64;
      const float* src = A + (long)(m0+arow)*DML + kb + aq*16;
      ra[0] = ((const f32x4*)src)[0]; ra[1] = ((const f32x4*)src)[1];
      ra[2] = ((const f32x4*)src)[2]; ra[3] = ((const f32x4*)src)[3];
      #pragma unroll
      for (int i=0;i<4;++i){
        int ci = i*256 + tid, row = ci>>3, kc = ci&7;
        rb[i] = *(const short8*)(B + (long)(n0+row)*DML + kb + kc*8);
      }
    }
    #pragma unroll
    for (int kk = 0; kk < 2; ++kk){
      short8 af[2], bfr[4];
      int cb = kk*4 + (lane >> 4);
      #pragma unroll
      for (int m_=0; m_<2; ++m_){
        int row = wrow + m_*16 + (lane & 15);
        af[m_] = *(const short8*)&sA[row*64 + ((cb ^ (row & 7)) << 3)];
      }
      #pragma unroll
      for (int n_=0; n_<4; ++n_){
        int row = wcol + n_*16 + (lane & 15);
        bfr[n_] = *(const short8*)&sB[row*64 + ((cb ^ (row & 7)) << 3)];
      }
      #pragma unroll
      for (int m_=0; m_<2; ++m_)
        #pragma unroll
        for (int n_=0; n_<4; ++n_)
          acc[m_][n_] = __builtin_amdgcn_mfma_f32_16x16x32_bf16(af[m_], bfr[n_], acc[m_][n_], 0, 0, 0);
    }
    __syncthreads();
    if (tt < 7){
      short8 o0, o1;
      #pragma unroll
      for (int j=0;j<4;++j){ o0[j]=(short)f2bf(ra[0][j]); o0[4+j]=(short)f2bf(ra[1][j]);
                             o1[j]=(short)f2bf(ra[2][j]); o1[4+j]=(short)f2bf(ra[3][j]); }
      int kc0 = aq*2, kc1 = aq*2+1;
      *(short8*)&sA[arow*64 + ((kc0 ^ (arow&7))<<3)] = o0;
      *(short8*)&sA[arow*64 + ((kc1 ^ (arow&7))<<3)] = o1;
      #pragma unroll
      for (int i=0;i<4;++i){
        int ci = i*256 + tid, row = ci>>3, kc = ci&7;
        *(short8*)&sB[row*64 + ((kc ^ (row&7))<<3)] = rb[i];
      }
      __syncthreads();
    }
  }

  #pragma unroll
  for (int m_=0;m_<2;++m_)
    #pragma unroll
    for (int n_=0;n_<4;++n_)
      #pragma unroll
      for (int rr=0;rr<4;++rr){
        int row = m0 + wrow + m_*16 + (lane>>4)*4 + rr;
        int col = n0 + wcol + n_*16 + (lane & 15);
        out[(long)row*DL + col] = f2bf(acc[m_][n_][rr] + bias[col]);
      }
}

// ---------- K3: [Q|K|V|A] = x @ [Wq|Wk|Wv|Wadd] ----------
__global__ __launch_bounds__(256) void k_gemm_qkva(const u16* __restrict__ A, const u16* __restrict__ B,
                                                   const float* __restrict__ badd,
                                                   u16* __restrict__ oq, u16* __restrict__ ok,
                                                   u16* __restrict__ ov, u16* __restrict__ oa){
  __shared__ u16 sA0[128*64], sB0[128*64], sA1[128*64], sB1[128*64];
  f32x4 acc[4][4];
  f32x4 z = {0.f,0.f,0.f,0.f};
  #pragma unroll
  for (int m_=0;m_<4;++m_) for (int n_=0;n_<4;++n_) acc[m_][n_] = z;
  int m0 = blockIdx.x*128;
  int tn = blockIdx.y;              // 0=Q 1=K 2=V 3=A
  gemm_core_db(A, B, DL, m0, tn*128, sA0, sB0, sA1, sB1, acc);
  int lane = threadIdx.x & 63, wave = threadIdx.x >> 6;
  int wrow = (wave>>1)*64, wcol = (wave&1)*64;
  u16* dst = (tn==0) ? oq : (tn==1) ? ok : (tn==2) ? ov : oa;
  #pragma unroll
  for (int m_=0;m_<4;++m_)
    #pragma unroll
    for (int n_=0;n_<4;++n_)
      #pragma unroll
      for (int r=0;r<4;++r){
        int row = m0 + wrow + m_*16 + (lane>>4)*4 + r;
        int cl  = (wcol + n_*16 + (lane & 15)) & 127;
        float v = acc[m_][n_][r];
        if (tn == 3) v += badd[cl];
        dst[(long)row*DM + cl] = f2bf(v);
      }
}

// ---------- K4: S[b] = Q[b] @ K[b]^T -> bf16 ----------
__global__ __launch_bounds__(256) void k_gemm_s(const u16* __restrict__ Q, const u16* __restrict__ Km,
                                                u16* __restrict__ S){
  __shared__ u16 sA0[128*64], sB0[128*64], sA1[128*64], sB1[128*64];
  f32x4 acc[4][4];
  f32x4 z = {0.f,0.f,0.f,0.f};
  #pragma unroll
  for (int m_=0;m_<4;++m_) for (int n_=0;n_<4;++n_) acc[m_][n_] = z;
  int b  = blockIdx.z;
  int m0 = blockIdx.x*128, n0 = blockIdx.y*128;
  const u16* A = Q  + (long)b*NN*DM;
  const u16* B = Km + (long)b*NN*DM;
  gemm_core_db(A, B, DM, m0, n0, sA0, sB0, sA1, sB1, acc);
  int lane = threadIdx.x & 63, wave = threadIdx.x >> 6;
  int wrow = (wave>>1)*64, wcol = (wave&1)*64;
  u16* Sb = S + (long)b*NN*NN;
  #pragma unroll
  for (int m_=0;m_<4;++m_)
    #pragma unroll
    for (int n_=0;n_<4;++n_)
      #pragma unroll
      for (int r=0;r<4;++r){
        int row = m0 + wrow + m_*16 + (lane>>4)*4 + r;
        int col = n0 + wcol + n_*16 + (lane & 15);
        Sb[(long)row*NN + col] = f2bf(acc[m_][n_][r]);
      }
}

// ---------- K5: M[b,l] = max_s S[b,l,idx[l,s]] - sum_s(...)/1024 ----------
__global__ void k_mscore(const u16* __restrict__ S, const int* __restrict__ idx, float* __restrict__ M){
  int g    = blockIdx.x*4 + (threadIdx.x >> 6);   // one wave per (b,l)
  int lane = threadIdx.x & 63;
  int b = g >> 10, l = g & 1023;
  const u16* Srow = S + (long)b*NN*NN + (long)l*NN;
  const int* ir = idx + l*SK;
  float mx = -1e30f, sm = 0.f;
  for (int s = lane; s < SK; s += 64){
    float v = bf2f(Srow[ir[s]]);
    mx = fmaxf(mx, v); sm += v;
  }
  #pragma unroll
  for (int o=32;o;o>>=1){ mx = fmaxf(mx, __shfl_xor(mx,o)); sm += __shfl_xor(sm,o); }
  if (lane == 0) M[g] = mx - sm * (1.0f/1024.0f);
}

// ---------- K6a: partial ranks (blocks 0..255) + V column-mean (blocks 256..271) ----------
__global__ __launch_bounds__(256) void k_rankvm(const float* __restrict__ M, int* __restrict__ partial,
                                                const u16* __restrict__ V, float* __restrict__ vmean){
  __shared__ float sC[64];
  __shared__ float red[16][128];
  int blk = blockIdx.x, t = threadIdx.x;
  if (blk < 256){
    int jc = blk & 15, b = blk >> 4;
    const float* Mb = M + b*NN;
    if (t < 64) sC[t] = Mb[jc*64 + t];
    __syncthreads();
    int j0 = jc*64;
    float mi[4];
    int cnt[4] = {0,0,0,0};
    #pragma unroll
    for (int r=0;r<4;++r) mi[r] = Mb[t + r*256];
    for (int j = 0; j < 64; ++j){
      float mj = sC[j];
      int jg = j0 + j;
      #pragma unroll
      for (int r=0;r<4;++r){
        int i = t + r*256;
        cnt[r] += (mj > mi[r]) || (mj == mi[r] && jg < i);
      }
    }
    int* pb = partial + (b*16 + jc)*NN;
    #pragma unroll
    for (int r=0;r<4;++r) pb[t + r*256] = cnt[r];
  } else {
    int b = blk - 256;
    int d8 = t & 15, seg = t >> 4;
    const u16* Vb = V + (long)b*KTOT + seg*64*DM + d8*8;
    float acc[8] = {0,0,0,0,0,0,0,0};
    for (int l = 0; l < 64; ++l){
      short8 v = *(const short8*)(Vb + l*DM);
      #pragma unroll
      for (int j=0;j<8;++j) acc[j] += bf2f((u16)v[j]);
    }
    #pragma unroll
    for (int j=0;j<8;++j) red[seg][d8*8+j] = acc[j];
    __syncthreads();
    if (t < 128){
      float s = 0.f;
      #pragma unroll
      for (int g=0;g<16;++g) s += red[g][t];
      vmean[b*DM + t] = s * (1.0f/1024.0f);
    }
  }
}

// ---------- K6b: sum partial ranks -> mtop + selmap ----------
__global__ __launch_bounds__(1024) void k_sel(const int* __restrict__ partial, int* __restrict__ mtop,
                                              int* __restrict__ selmap){
  int b = blockIdx.x, i = threadIdx.x;
  int cnt = 0;
  #pragma unroll
  for (int jc = 0; jc < 16; ++jc) cnt += partial[(b*16 + jc)*NN + i];
  selmap[b*NN + i] = (cnt < SK) ? cnt : -1;
  if (cnt < SK) mtop[b*SK + cnt] = i;
}

// ---------- K9: softmax(S_row/sqrt(d)) @ V for top-140 rows, 4 rows/block ----------
// PV: dg = t&15 (d fast-varying => coalesced V loads: each wave-load = 4 full rows),
// kg = t>>4; cross-kg reduce = shfl_xor(16,32) + LDS cross-wave.
__global__ __launch_bounds__(256) void k_attn(const u16* __restrict__ S, const u16* __restrict__ V,
                                              const int* __restrict__ mtop, float* __restrict__ upd){
  __shared__ float sE[4][1024];
  __shared__ float redM[4][4];
  __shared__ float redS[4][4];
  __shared__ float sP[4][4][128];   // [wave][row][d] 8KB
  int b = blockIdx.y, u0 = blockIdx.x*4, t = threadIdx.x;
  int lane = t & 63, wave = t >> 6;
  const float inv = 0.08838834764831845f;   // 1/sqrt(128)

  int rows[4];
  #pragma unroll
  for (int r=0;r<4;++r) rows[r] = mtop[b*SK + u0 + r];

  float sv[4][4];
  float pm[4];
  const u16* Sb = S + (long)b*NN*NN;
  #pragma unroll
  for (int r=0;r<4;++r){
    ushort4 raw = ((const ushort4*)(Sb + (long)rows[r]*NN))[t];
    sv[r][0] = bf2f(raw.x)*inv; sv[r][1] = bf2f(raw.y)*inv;
    sv[r][2] = bf2f(raw.z)*inv; sv[r][3] = bf2f(raw.w)*inv;
    pm[r] = fmaxf(fmaxf(sv[r][0],sv[r][1]), fmaxf(sv[r][2],sv[r][3]));
  }
  #pragma unroll
  for (int o=32;o;o>>=1)
    #pragma unroll
    for (int r=0;r<4;++r) pm[r] = fmaxf(pm[r], __shfl_xor(pm[r],o));
  if (lane == 0){
    #pragma unroll
    for (int r=0;r<4;++r) redM[wave][r] = pm[r];
  }
  __syncthreads();
  float mx[4], ps[4];
  #pragma unroll
  for (int r=0;r<4;++r)
    mx[r] = fmaxf(fmaxf(redM[0][r],redM[1][r]), fmaxf(redM[2][r],redM[3][r]));
  #pragma unroll
  for (int r=0;r<4;++r){
    float s = 0.f;
    #pragma unroll
    for (int j=0;j<4;++j){
      float e = __expf(sv[r][j] - mx[r]);
      sE[r][t*4+j] = e;
      s += e;
    }
    ps[r] = s;
  }
  #pragma unroll
  for (int o=32;o;o>>=1)
    #pragma unroll
    for (int r=0;r<4;++r) ps[r] += __shfl_xor(ps[r],o);
  if (lane == 0){
    #pragma unroll
    for (int r=0;r<4;++r) redS[wave][r] = ps[r];
  }
  __syncthreads();
  float rZ[4];
  #pragma unroll
  for (int r=0;r<4;++r)
    rZ[r] = 1.0f / (redS[0][r]+redS[1][r]+redS[2][r]+redS[3][r]);

  // ---- PV, coalesced: dg = t&15, kg = t>>4 ----
  int dg = t & 15;
  int kg = t >> 4;
  const u16* Vb = V + (long)b*KTOT + dg*8;
  float acc[4][8];
  #pragma unroll
  for (int r=0;r<4;++r)
    #pragma unroll
    for (int j=0;j<8;++j) acc[r][j] = 0.f;

  for (int k = kg; k < NN; k += 16){
    short8 v = *(const short8*)(Vb + (long)k*DM);
    float vf[8];
    #pragma unroll
    for (int j=0;j<8;++j) vf[j] = bf2f((u16)v[j]);
    #pragma unroll
    for (int r=0;r<4;++r){
      float e = sE[r][k];
      #pragma unroll
      for (int j=0;j<8;++j) acc[r][j] += e * vf[j];
    }
  }

  // reduce over this wave's 4 kg values (lane bits 4,5)
  #pragma unroll
  for (int o=16;o<64;o<<=1)
    #pragma unroll
    for (int r=0;r<4;++r)
      #pragma unroll
      for (int j=0;j<8;++j) acc[r][j] += __shfl_xor(acc[r][j], o);

  if ((t & 63) < 16){
    #pragma unroll
    for (int r=0;r<4;++r)
      #pragma unroll
      for (int j=0;j<8;++j) sP[wave][r][dg*8+j] = acc[r][j];
  }
  __syncthreads();
  if (t < 128){
    #pragma unroll
    for (int r=0;r<4;++r){
      float s = sP[0][r][t] + sP[1][r][t] + sP[2][r][t] + sP[3][r][t];
      upd[((long)b*SK + u0 + r)*DM + t] = s * rZ[r];
    }
  }
}

// ---------- K11: final GEMV partials: (ctx+A) @ W_final ----------
__global__ __launch_bounds__(256) void k_final(const float* __restrict__ upd, const float* __restrict__ vmean,
                                               const int* __restrict__ selmap,
                                               const u16* __restrict__ Aad,
                                               const u16* __restrict__ wfT, float* __restrict__ part){
  int b = blockIdx.x, ch = blockIdx.y, t = threadIdx.x;
  long base = (long)b * KTOT;
  int k0 = ch * 4096;
  float acc[NC] = {0.f};
  for (int k = k0 + t; k < k0 + 4096; k += 256){
    int l = k >> 7, d = k & 127;
    int sel = selmap[b*NN + l];
    float c = (sel >= 0) ? upd[((long)b*SK + sel)*DM + d] : vmean[b*DM + d];
    float v = c + bf2f(Aad[base + k]);
    #pragma unroll
    for (int cc = 0; cc < NC; ++cc) acc[cc] += v * bf2f(wfT[cc*KTOT + k]);
  }
  __shared__ float lred[40];
  int lane = t & 63, wave = t >> 6;
  #pragma unroll
  for (int c = 0; c < NC; ++c){
    float v = acc[c];
    #pragma unroll
    for (int o=32;o;o>>=1) v += __shfl_xor(v,o);
    if (lane == 0) lred[wave*NC + c] = v;
  }
  __syncthreads();
  if (t < NC) part[(b*32 + ch)*NC + t] = lred[t] + lred[NC+t] + lred[2*NC+t] + lred[3*NC+t];
}

// ---------- K12: reduce partials + bias -> out ----------
__global__ void k_out(const float* __restrict__ part, const float* __restrict__ bfin, float* __restrict__ out){
  int t = threadIdx.x;
  if (t < BB*NC){
    int b = t / NC, c = t % NC;
    float s = bfin[c];
    #pragma unroll
    for (int ch = 0; ch < 32; ++ch) s += part[(b*32 + ch)*NC + c];
    out[t] = s;
  }
}

// ---------- launch ----------
extern "C" void kernel_launch(void* const* d_in, const int* in_sizes, int n_in,
                              void* d_out, int out_size, void* d_ws, size_t ws_size,
                              hipStream_t stream){
  const float* emb  = (const float*)d_in[0];
  const int*   idxs = (const int*)  d_in[1];
  const float* Wlin = (const float*)d_in[2];
  const float* blin = (const float*)d_in[3];
  const float* Wq   = (const float*)d_in[4];
  const float* Wk   = (const float*)d_in[5];
  const float* Wv   = (const float*)d_in[6];
  const float* Wadd = (const float*)d_in[7];
  const float* badd = (const float*)d_in[8];
  const float* Wfin = (const float*)d_in[9];
  const float* bfin = (const float*)d_in[10];
  float* out = (float*)d_out;

  char* p = (char*)d_ws;
  auto alloc = [&](size_t bytes)->char*{ char* r = p; p += (bytes + 255) & ~(size_t)255; return r; };
  u16*   wlinT  = (u16*)  alloc((size_t)DL*DML*2);
  u16*   w4T    = (u16*)  alloc((size_t)4*DM*DL*2);
  u16*   x_bf   = (u16*)  alloc((size_t)BB*NN*DL*2);
  u16*   q_bf   = (u16*)  alloc((size_t)BB*NN*DM*2);
  u16*   k_bf   = (u16*)  alloc((size_t)BB*NN*DM*2);
  u16*   v_bf   = (u16*)  alloc((size_t)BB*NN*DM*2);
  u16*   a_bf   = (u16*)  alloc((size_t)BB*NN*DM*2);
  u16*   s_bf   = (u16*)  alloc((size_t)BB*NN*NN*2);
  float* m_f    = (float*)alloc((size_t)BB*NN*4);
  int*   rankp  = (int*)  alloc((size_t)BB*16*NN*4);
  int*   mtop   = (int*)  alloc((size_t)BB*SK*4);
  int*   selmap = (int*)  alloc((size_t)BB*NN*4);
  float* vmean  = (float*)alloc((size_t)BB*DM*4);
  float* upd    = (float*)alloc((size_t)BB*SK*DM*4);
  u16*   wfT    = (u16*)  alloc((size_t)NC*KTOT*2);
  float* part   = (float*)alloc((size_t)BB*32*NC*4);

  // 1: pack weights + wfT
  k_prep<<<dim3(1024), dim3(256), 0, stream>>>(Wlin, Wq, Wk, Wv, Wadd, wlinT, w4T, Wfin, wfT);
  // 2: x = emb @ Wlin + b  (BN=128 split for 2x occupancy)
  k_gemm_x<<<dim3(256, 2), dim3(256), 0, stream>>>(emb, wlinT, blin, x_bf);
  // 3: Q,K,V,A
  k_gemm_qkva<<<dim3(128, 4), dim3(256), 0, stream>>>(x_bf, w4T, badd, q_bf, k_bf, v_bf, a_bf);
  // 4: S = Q K^T per batch
  k_gemm_s<<<dim3(8, 8, 16), dim3(256), 0, stream>>>(q_bf, k_bf, s_bf);
  // 5: M scores
  k_mscore<<<dim3(BB*NN/4), dim3(256), 0, stream>>>(s_bf, idxs, m_f);
  // 6: partial ranks + vmean
  k_rankvm<<<dim3(272), dim3(256), 0, stream>>>(m_f, rankp, v_bf, vmean);
  // 7: select top-140
  k_sel<<<dim3(BB), dim3(1024), 0, stream>>>(rankp, mtop, selmap);
  // 8: attention rows -> compact upd (coalesced PV)
  k_attn<<<dim3(SK/4, BB), dim3(256), 0, stream>>>(s_bf, v_bf, mtop, upd);
  // 9/10: final projection
  k_final<<<dim3(BB, 32), dim3(256), 0, stream>>>(upd, vmean, selmap, a_bf, wfT, part);
  k_out<<<dim3(1), dim3(256), 0, stream>>>(part, bfin, out);
}